// Round 12
// baseline (974.657 us; speedup 1.0000x reference)
//
#include <hip/hip_runtime.h>

#define NUSER 100000
#define NITEM 50000
#define NEDGE 640000
#define NLINK 200000
#define GI 49     // ceil(NITEM/1024)  scan chunks
#define GU 98     // ceil(NUSER/1024)
#define NB1U 782  // ceil(NUSER/128)  L1 gemm row-blocks
#define NB1I 391  // ceil(NITEM/128)
#define NB1G (2 * (NB1U + NB1I))   // 2346: rowblk-major, cg(2) minor
#define NBU 391   // ceil(NUSER/256)  L2 gemm row-blocks
#define NBI 196   // ceil(NITEM/256)
#define NBG2 (2 * (NBU + NBI))     // 1174
#define WNODE 512 // fill/count node-window size (owned by ONE block -> LDS counters)
#define NWI 98    // ceil(NITEM/512)
#define NWU 196   // ceil(NUSER/512)
#define NWF (NWI + NWU)            // 294 window blocks
#define NWPREP 24 // wprep blocks at 512 thr (12288 threads total)
// F0 = F1 = 128, F2 = 64

typedef unsigned int  uint;
typedef unsigned short ushort_t;
typedef __attribute__((ext_vector_type(8))) short bf16x8;
typedef __attribute__((ext_vector_type(4))) float f32x4;
typedef __attribute__((ext_vector_type(4))) uint  u32x4;

__device__ __forceinline__ ushort_t f2bf(float f) {           // RNE f32 -> bf16
    uint u = __float_as_uint(f);
    u += 0x7FFFu + ((u >> 16) & 1u);
    return (ushort_t)(u >> 16);
}
__device__ __forceinline__ float bf2f(ushort_t h) { return __uint_as_float(((uint)h) << 16); }
__device__ __forceinline__ float lo16f(uint u) { return __uint_as_float(u << 16); }
__device__ __forceinline__ float hi16f(uint u) { return __uint_as_float(u & 0xFFFF0000u); }

// ---------------------------------------------------------------------------
// Fused [window degree-count (LDS counters, NO global atomics) | weight pack].
// Blocks [0,NWF): each owns a 512-node window, scans the full edge key array
// (L2-resident), counts in LDS, stores cnt wholesale. Blocks [NWF,NWF+24):
// pack the 4 B=[Wl|Wr] pairs into MFMA fragment order, bf16 hi/lo.
// ---------------------------------------------------------------------------
__global__ __launch_bounds__(512) void countw_kernel(
    const int* __restrict__ src, const int* __restrict__ dst,
    int* __restrict__ cnt_u, int* __restrict__ cnt_i,
    const float* __restrict__ Wl0, const float* __restrict__ Wr0,
    const float* __restrict__ Wl1, const float* __restrict__ Wr1,
    const float* __restrict__ Wl2, const float* __restrict__ Wr2,
    const float* __restrict__ Wl3, const float* __restrict__ Wr3,
    ushort_t* __restrict__ Bh0, ushort_t* __restrict__ Bl0,
    ushort_t* __restrict__ Bh1, ushort_t* __restrict__ Bl1,
    ushort_t* __restrict__ Bh2, ushort_t* __restrict__ Bl2,
    ushort_t* __restrict__ Bh3, ushort_t* __restrict__ Bl3)
{
    __shared__ int wcnt[WNODE];
    int b = blockIdx.x;
    if (b < NWF) {
        const int* key; int* cnt; int n, lo;
        if (b < NWI) { key = dst; cnt = cnt_i; n = NITEM; lo = b * WNODE; }
        else         { key = src; cnt = cnt_u; n = NUSER; lo = (b - NWI) * WNODE; }
        int hi = min(lo + WNODE, n);
        wcnt[threadIdx.x] = 0;
        __syncthreads();
        for (int e = threadIdx.x; e < NEDGE; e += 512) {
            int k = key[e];
            if (k >= lo && k < hi) atomicAdd(&wcnt[k - lo], 1);   // LDS atomic
        }
        __syncthreads();
        int node = lo + threadIdx.x;
        if (node < hi) cnt[node] = wcnt[threadIdx.x];
        return;
    }
    int g = (b - NWF) * 512 + threadIdx.x;   // [0, 12288)
    const float *Wl, *Wr; ushort_t *Bh, *Bl; int FO, t;
    if (g < 4096)       { Wl = Wl0; Wr = Wr0; Bh = Bh0; Bl = Bl0; FO = 128; t = g; }
    else if (g < 8192)  { Wl = Wl1; Wr = Wr1; Bh = Bh1; Bl = Bl1; FO = 128; t = g - 4096; }
    else if (g < 10240) { Wl = Wl2; Wr = Wr2; Bh = Bh2; Bl = Bl2; FO = 64;  t = g - 8192; }
    else                { Wl = Wl3; Wr = Wr3; Bh = Bh3; Bl = Bl3; FO = 64;  t = g - 10240; }
    int lane = t & 63, ks = (t >> 6) & 3, nt = t >> 8;
    int col = nt * 16 + (lane & 15);
    int k0 = ks * 32 + (lane >> 4) * 8;
    const float* W = (col < FO) ? Wl : Wr;
    int cc = (col < FO) ? col : col - FO;
#pragma unroll
    for (int j = 0; j < 8; ++j) {
        float v = W[(size_t)(k0 + j) * FO + cc];
        ushort_t h = f2bf(v);
        Bh[(size_t)t * 8 + j] = h;
        Bl[(size_t)t * 8 + j] = f2bf(v - bf2f(h));
    }
}

// ---------------------------------------------------------------------------
// Ordered exclusive scan (unchanged). head = START offsets, now read-only
// downstream (fill no longer mutates it).
// ---------------------------------------------------------------------------
__global__ __launch_bounds__(256) void scan1_kernel(
    const int* __restrict__ cnt_i, const int* __restrict__ cnt_u,
    int* __restrict__ head_i, int* __restrict__ head_u,
    int* __restrict__ bsum_i, int* __restrict__ bsum_u)
{
    __shared__ int sh[256];
    int b = blockIdx.x, t = threadIdx.x;
    const int* cnt; int* head; int* bsum; int n, cb;
    if (b < GI) { cnt = cnt_i; head = head_i; bsum = bsum_i; n = NITEM; cb = b; }
    else        { cnt = cnt_u; head = head_u; bsum = bsum_u; n = NUSER; cb = b - GI; }
    int base = cb * 1024 + t * 4;
    int4 v = {0, 0, 0, 0};
    if (base + 3 < n) v = *(const int4*)(cnt + base);
    else {
        if (base + 0 < n) v.x = cnt[base + 0];
        if (base + 1 < n) v.y = cnt[base + 1];
        if (base + 2 < n) v.z = cnt[base + 2];
    }
    int s = v.x + v.y + v.z + v.w;
    sh[t] = s;
    __syncthreads();
    for (int o = 1; o < 256; o <<= 1) {
        int a = (t >= o) ? sh[t - o] : 0;
        __syncthreads();
        sh[t] += a;
        __syncthreads();
    }
    int excl = sh[t] - s;
    if (t == 255) bsum[cb] = sh[255];
    if (base + 0 < n) head[base + 0] = excl;
    if (base + 1 < n) head[base + 1] = excl + v.x;
    if (base + 2 < n) head[base + 2] = excl + v.x + v.y;
    if (base + 3 < n) head[base + 3] = excl + v.x + v.y + v.z;
}

__global__ __launch_bounds__(256) void scan23_kernel(
    int* __restrict__ head_i, int* __restrict__ head_u,
    const int* __restrict__ bsum_i, const int* __restrict__ bsum_u)
{
    __shared__ int sh[256];
    int b = blockIdx.x, t = threadIdx.x;
    int* head; const int* bsum; int n, cb;
    if (b < GI) { head = head_i; bsum = bsum_i; n = NITEM; cb = b; }
    else        { head = head_u; bsum = bsum_u; n = NUSER; cb = b - GI; }
    sh[t] = (t < cb) ? bsum[t] : 0;
    __syncthreads();
    for (int o = 128; o >= 1; o >>= 1) {
        if (t < o) sh[t] += sh[t + o];
        __syncthreads();
    }
    int add = sh[0];
    int base = cb * 1024 + t * 4;
#pragma unroll
    for (int k = 0; k < 4; ++k)
        if (base + k < n) head[base + k] += add;
}

// ---------------------------------------------------------------------------
// L1 GEMM body (r11, verified): block = 128 rows x ONE 128-col group.
// A-split-only numerics, Bh LDS-resident (32KB), C bounced through LDS.
// ---------------------------------------------------------------------------
__device__ __forceinline__ void gemm1_body(
    const float* __restrict__ A, const ushort_t* __restrict__ Bcg,
    ushort_t* __restrict__ dstp, int n, int row0, u32x4* __restrict__ bsh)
{
#pragma unroll
    for (int i = 0; i < 4; ++i)
        bsh[i * 512 + threadIdx.x] = ((const u32x4*)Bcg)[i * 512 + threadIdx.x];
    __syncthreads();

    const int lane = threadIdx.x & 63, wv = threadIdx.x >> 6;
    const int lr = lane & 15, lg = lane >> 4;
    const int r0 = row0 + wv * 16 + lr;
    const bool rv = r0 < n;
    const float* arow = A + (size_t)r0 * 128;

    f32x4 acc[8];
#pragma unroll
    for (int ct = 0; ct < 8; ++ct) { f32x4 zz = {0.f, 0.f, 0.f, 0.f}; acc[ct] = zz; }

    f32x4 fa, fb;
#define LOAD_A1(KS)                                                            \
    {                                                                          \
        fa = f32x4{0.f, 0.f, 0.f, 0.f}; fb = fa;                               \
        if (rv) {                                                              \
            const f32x4* p = (const f32x4*)(arow + (KS) * 32 + lg * 8);        \
            fa = p[0]; fb = p[1];                                              \
        }                                                                      \
    }

    LOAD_A1(0);
#pragma unroll
    for (int ks = 0; ks < 4; ++ks) {
        float e0s[4] = {fa[0], fa[2], fb[0], fb[2]};
        float e1s[4] = {fa[1], fa[3], fb[1], fb[3]};
        uint hv[4], lv[4];
#pragma unroll
        for (int j = 0; j < 4; ++j) {
            uint au = __float_as_uint(e0s[j]);
            uint bu = __float_as_uint(e1s[j]);
            uint ah_ = au & 0xFFFF0000u, bh_ = bu & 0xFFFF0000u;
            hv[j] = (au >> 16) | bh_;
            float l0 = e0s[j] - __uint_as_float(ah_);   // exact residual
            float l1 = e1s[j] - __uint_as_float(bh_);
            lv[j] = (__float_as_uint(l0) >> 16) | (__float_as_uint(l1) & 0xFFFF0000u);
        }
        u32x4 hq = {hv[0], hv[1], hv[2], hv[3]};
        u32x4 lq = {lv[0], lv[1], lv[2], lv[3]};
        bf16x8 ahf = __builtin_bit_cast(bf16x8, hq);
        bf16x8 alf = __builtin_bit_cast(bf16x8, lq);
        if (ks < 3) LOAD_A1(ks + 1);   // prefetch next ks under the MFMAs

#pragma unroll
        for (int ct = 0; ct < 8; ++ct) {
            bf16x8 bh = __builtin_bit_cast(bf16x8, bsh[(ct * 4 + ks) * 64 + lane]);
            acc[ct] = __builtin_amdgcn_mfma_f32_16x16x32_bf16(ahf, bh, acc[ct], 0, 0, 0);
            acc[ct] = __builtin_amdgcn_mfma_f32_16x16x32_bf16(alf, bh, acc[ct], 0, 0, 0);
        }
    }
#undef LOAD_A1

    // ---- C bounce: acc -> LDS (B no longer needed) -> coalesced store ----
    __syncthreads();
    ushort_t* cl = (ushort_t*)bsh;     // 128 x 128 bf16 = 32KB, exact fit
#pragma unroll
    for (int ct = 0; ct < 8; ++ct) {
        int col = ct * 16 + lr;        // m89 layout: col=lane&15, row=(lane>>4)*4+r
#pragma unroll
        for (int r = 0; r < 4; ++r)
            cl[(wv * 16 + lg * 4 + r) * 128 + col] = f2bf(acc[ct][r]);
    }
    __syncthreads();
    int row = threadIdx.x >> 2, seg = threadIdx.x & 3;
    int grow = row0 + row;
    if (grow < n) {
        const u32x4* s = (const u32x4*)(cl + row * 128) + seg * 4;
        u32x4* d = (u32x4*)(dstp + (size_t)grow * 128) + seg * 4;
        d[0] = s[0]; d[1] = s[1]; d[2] = s[2]; d[3] = s[3];   // 64B/thread
    }
}

// ---------------------------------------------------------------------------
// Fused [layer-1 GEMM | window-owner CSR fill].
// Fill blocks [NB1G, NB1G+NWF): each owns a 512-node window; scans the full
// edge key array; position = head[k] (read-only) + LDS-atomic local count.
// ZERO global atomics; each window's nbr slice written by one CU (one XCD)
// -> no cross-XCD counter ping-pong, no shared-line write amplification.
// ---------------------------------------------------------------------------
__global__ __launch_bounds__(512) void gemmfill_kernel(
    const float* __restrict__ xu, const float* __restrict__ xi,
    const ushort_t* __restrict__ Bh0, const ushort_t* __restrict__ Bh1,
    ushort_t* __restrict__ y0, ushort_t* __restrict__ z0,
    ushort_t* __restrict__ y1, ushort_t* __restrict__ z1,
    const int* __restrict__ src, const int* __restrict__ dst,
    const int* __restrict__ head_i, const int* __restrict__ head_u,
    int* __restrict__ nbr_i, int* __restrict__ nbr_u)
{
    __shared__ u32x4 bsh[2048];   // 32KB (gemm: Bh slice then C bounce; fill: wcnt)
    if (blockIdx.x >= NB1G) {
        int b = blockIdx.x - NB1G;
        int* wcnt = (int*)bsh;
        const int *key, *val, *head; int* nbr; int n, lo;
        if (b < NWI) { key = dst; val = src; head = head_i; nbr = nbr_i; n = NITEM; lo = b * WNODE; }
        else         { key = src; val = dst; head = head_u; nbr = nbr_u; n = NUSER; lo = (b - NWI) * WNODE; }
        int hi = min(lo + WNODE, n);
        wcnt[threadIdx.x] = 0;
        __syncthreads();
        for (int e = threadIdx.x; e < NEDGE; e += 512) {
            int k = key[e];
            if (k >= lo && k < hi) {
                int pos = head[k] + atomicAdd(&wcnt[k - lo], 1);   // LDS atomic
                nbr[pos] = val[e];
            }
        }
        return;
    }
    int bid = blockIdx.x;
    if (bid < 2 * NB1U) {
        int rowblk = bid >> 1, cg = bid & 1;
        gemm1_body(xu, Bh0 + (size_t)cg * 16384, cg ? z0 : y0, NUSER, rowblk * 128, bsh);
    } else {
        int b2 = bid - 2 * NB1U;
        int rowblk = b2 >> 1, cg = b2 & 1;
        gemm1_body(xi, Bh1 + (size_t)cg * 16384, cg ? z1 : y1, NITEM, rowblk * 128, bsh);
    }
}

// ---------------------------------------------------------------------------
// L2 GEMM body (r9, verified): 256 rows x 64-col group, bf16 A exact,
// B hi+lo in LDS (16+16KB), 2 products, no k-loop barriers.
// ---------------------------------------------------------------------------
__device__ __forceinline__ void gemm2_body(
    const ushort_t* __restrict__ A,
    const ushort_t* __restrict__ Bh, const ushort_t* __restrict__ Bl,
    ushort_t* __restrict__ dstp, int n, int row0,
    u32x4* __restrict__ bshH, u32x4* __restrict__ bshL)
{
#pragma unroll
    for (int i = 0; i < 2; ++i) {
        int idx = i * 512 + threadIdx.x;
        bshH[idx] = ((const u32x4*)Bh)[idx];
        bshL[idx] = ((const u32x4*)Bl)[idx];
    }
    __syncthreads();

    const int lane = threadIdx.x & 63, wv = threadIdx.x >> 6;
    const int lr = lane & 15, lg = lane >> 4;
    const int wrow0 = row0 + wv * 32;
    const int r0 = wrow0 + lr, r1 = wrow0 + 16 + lr;

    f32x4 acc[2][4];
#pragma unroll
    for (int rt = 0; rt < 2; ++rt)
#pragma unroll
        for (int ct = 0; ct < 4; ++ct) { f32x4 zz = {0.f, 0.f, 0.f, 0.f}; acc[rt][ct] = zz; }

    u32x4 qc[2];
#define LOAD_A2(KS)                                                            \
    {                                                                          \
        int kb = (KS) * 32 + lg * 8;                                           \
        int rows[2] = {r0, r1};                                                \
        _Pragma("unroll")                                                      \
        for (int rt = 0; rt < 2; ++rt) {                                       \
            qc[rt] = u32x4{0u, 0u, 0u, 0u};                                    \
            if (rows[rt] < n)                                                  \
                qc[rt] = *(const u32x4*)(A + (size_t)rows[rt] * 128 + kb);     \
        }                                                                      \
    }

    LOAD_A2(0);
#pragma unroll
    for (int ks = 0; ks < 4; ++ks) {
        bf16x8 ah[2];
#pragma unroll
        for (int rt = 0; rt < 2; ++rt) ah[rt] = __builtin_bit_cast(bf16x8, qc[rt]);
        if (ks < 3) LOAD_A2(ks + 1);

#pragma unroll
        for (int ct = 0; ct < 4; ++ct) {
            bf16x8 bh = __builtin_bit_cast(bf16x8, bshH[(ct * 4 + ks) * 64 + lane]);
            bf16x8 bl = __builtin_bit_cast(bf16x8, bshL[(ct * 4 + ks) * 64 + lane]);
#pragma unroll
            for (int rt = 0; rt < 2; ++rt) {
                acc[rt][ct] = __builtin_amdgcn_mfma_f32_16x16x32_bf16(ah[rt], bh, acc[rt][ct], 0, 0, 0);
                acc[rt][ct] = __builtin_amdgcn_mfma_f32_16x16x32_bf16(ah[rt], bl, acc[rt][ct], 0, 0, 0);
            }
        }
    }
#undef LOAD_A2

#pragma unroll
    for (int rt = 0; rt < 2; ++rt)
#pragma unroll
        for (int ct = 0; ct < 4; ++ct) {
            int cc = ct * 16 + lr;
#pragma unroll
            for (int r = 0; r < 4; ++r) {
                int orow = wrow0 + rt * 16 + lg * 4 + r;
                if (orow < n) dstp[(size_t)orow * 64 + cc] = f2bf(acc[rt][ct][r]);
            }
        }
}

__global__ __launch_bounds__(512) void gemm2_kernel(
    const ushort_t* __restrict__ A0, const ushort_t* __restrict__ A1,
    const ushort_t* __restrict__ Bh0, const ushort_t* __restrict__ Bl0,
    const ushort_t* __restrict__ Bh1, const ushort_t* __restrict__ Bl1,
    ushort_t* __restrict__ y0, ushort_t* __restrict__ z0,
    ushort_t* __restrict__ y1, ushort_t* __restrict__ z1)
{
    __shared__ u32x4 bshH[1024];   // 16KB
    __shared__ u32x4 bshL[1024];   // 16KB
    int bid = blockIdx.x;
    if (bid < 2 * NBU) {
        int rowblk = bid >> 1, cg = bid & 1;
        gemm2_body(A0, Bh0 + (size_t)cg * 8192, Bl0 + (size_t)cg * 8192,
                   cg ? z0 : y0, NUSER, rowblk * 256, bshH, bshL);
    } else {
        int b2 = bid - 2 * NBU;
        int rowblk = b2 >> 1, cg = b2 & 1;
        gemm2_body(A1, Bh1 + (size_t)cg * 8192, Bl1 + (size_t)cg * 8192,
                   cg ? z1 : y1, NITEM, rowblk * 256, bshH, bshL);
    }
}

// ---------------------------------------------------------------------------
// Layer-1 gather + epilogue. head = START offsets now: slice = [j, j+c).
// ---------------------------------------------------------------------------
__global__ __launch_bounds__(256) void gather1_kernel(
    const ushort_t* __restrict__ ymsg_u, const ushort_t* __restrict__ ymsg_i,
    const int* __restrict__ nbr_i, const int* __restrict__ head_i, const int* __restrict__ cnt_i,
    const int* __restrict__ nbr_u, const int* __restrict__ head_u, const int* __restrict__ cnt_u,
    const ushort_t* __restrict__ z_i, const ushort_t* __restrict__ z_u,
    const float* __restrict__ b_ui, const float* __restrict__ b_iu,
    ushort_t* __restrict__ h1_i, ushort_t* __restrict__ h1_u)
{
    int w = (blockIdx.x << 2) + (threadIdx.x >> 6);
    const ushort_t *ym, *z; const int *nbr, *head, *cnt; const float* bias;
    ushort_t* hout; int node;
    if (w < NITEM) { ym = ymsg_u; nbr = nbr_i; head = head_i; cnt = cnt_i; z = z_i; bias = b_ui; hout = h1_i; node = w; }
    else if (w < NITEM + NUSER) { ym = ymsg_i; nbr = nbr_u; head = head_u; cnt = cnt_u; z = z_u; bias = b_iu; hout = h1_u; node = w - NITEM; }
    else return;
    int lane = threadIdx.x & 63;
    int c = cnt[node];
    int j = head[node];
    int end = j + c;
    const uint* Y = (const uint*)ym;
    float ax = 0.f, ay = 0.f;
    for (; j + 7 < end; j += 8) {
        uint u0 = Y[(size_t)nbr[j + 0] * 64 + lane];
        uint u1 = Y[(size_t)nbr[j + 1] * 64 + lane];
        uint u2 = Y[(size_t)nbr[j + 2] * 64 + lane];
        uint u3 = Y[(size_t)nbr[j + 3] * 64 + lane];
        uint u4 = Y[(size_t)nbr[j + 4] * 64 + lane];
        uint u5 = Y[(size_t)nbr[j + 5] * 64 + lane];
        uint u6 = Y[(size_t)nbr[j + 6] * 64 + lane];
        uint u7 = Y[(size_t)nbr[j + 7] * 64 + lane];
        ax += lo16f(u0) + lo16f(u1) + lo16f(u2) + lo16f(u3)
            + lo16f(u4) + lo16f(u5) + lo16f(u6) + lo16f(u7);
        ay += hi16f(u0) + hi16f(u1) + hi16f(u2) + hi16f(u3)
            + hi16f(u4) + hi16f(u5) + hi16f(u6) + hi16f(u7);
    }
    for (; j + 1 < end; j += 2) {
        uint u0 = Y[(size_t)nbr[j + 0] * 64 + lane];
        uint u1 = Y[(size_t)nbr[j + 1] * 64 + lane];
        ax += lo16f(u0) + lo16f(u1);
        ay += hi16f(u0) + hi16f(u1);
    }
    if (j < end) {
        uint u0 = Y[(size_t)nbr[j] * 64 + lane];
        ax += lo16f(u0); ay += hi16f(u0);
    }
    float m = 1.f / fmaxf((float)c, 1.f);
    uint zu = ((const uint*)z)[(size_t)node * 64 + lane];
    float vx = fmaxf(ax * m + lo16f(zu) + bias[lane * 2], 0.f);
    float vy = fmaxf(ay * m + hi16f(zu) + bias[lane * 2 + 1], 0.f);
    ((uint*)hout)[(size_t)node * 64 + lane] = (uint)f2bf(vx) | ((uint)f2bf(vy) << 16);
}

// ---------------------------------------------------------------------------
// Layer-2 gather + epilogue. head = START offsets: slice = [j, j+c).
// ---------------------------------------------------------------------------
__global__ __launch_bounds__(256) void gather2_kernel(
    const ushort_t* __restrict__ ymsg_u, const ushort_t* __restrict__ ymsg_i,
    const int* __restrict__ nbr_i, const int* __restrict__ head_i, const int* __restrict__ cnt_i,
    const int* __restrict__ nbr_u, const int* __restrict__ head_u, const int* __restrict__ cnt_u,
    const ushort_t* __restrict__ z_i, const ushort_t* __restrict__ z_u,
    const float* __restrict__ b_ui, const float* __restrict__ b_iu,
    ushort_t* __restrict__ h2_i, ushort_t* __restrict__ h2_u)
{
    int w = (blockIdx.x << 2) + (threadIdx.x >> 6);
    const ushort_t *ym, *z; const int *nbr, *head, *cnt; const float* bias;
    ushort_t* hout; int node;
    if (w < NITEM) { ym = ymsg_u; nbr = nbr_i; head = head_i; cnt = cnt_i; z = z_i; bias = b_ui; hout = h2_i; node = w; }
    else if (w < NITEM + NUSER) { ym = ymsg_i; nbr = nbr_u; head = head_u; cnt = cnt_u; z = z_u; bias = b_iu; hout = h2_u; node = w - NITEM; }
    else return;
    int lane = threadIdx.x & 63;
    int c = cnt[node];
    int j = head[node];
    int end = j + c;
    float a = 0.f;
    for (; j + 7 < end; j += 8) {
        a += bf2f(ym[(size_t)nbr[j + 0] * 64 + lane]) + bf2f(ym[(size_t)nbr[j + 1] * 64 + lane])
           + bf2f(ym[(size_t)nbr[j + 2] * 64 + lane]) + bf2f(ym[(size_t)nbr[j + 3] * 64 + lane])
           + bf2f(ym[(size_t)nbr[j + 4] * 64 + lane]) + bf2f(ym[(size_t)nbr[j + 5] * 64 + lane])
           + bf2f(ym[(size_t)nbr[j + 6] * 64 + lane]) + bf2f(ym[(size_t)nbr[j + 7] * 64 + lane]);
    }
    for (; j + 1 < end; j += 2)
        a += bf2f(ym[(size_t)nbr[j] * 64 + lane]) + bf2f(ym[(size_t)nbr[j + 1] * 64 + lane]);
    if (j < end) a += bf2f(ym[(size_t)nbr[j] * 64 + lane]);
    float m = 1.f / fmaxf((float)c, 1.f);
    float v = a * m + bf2f(z[(size_t)node * 64 + lane]) + bias[lane];
    hout[(size_t)node * 64 + lane] = f2bf(v);
}

// ---------------------------------------------------------------------------
// Link head (unchanged).
// ---------------------------------------------------------------------------
__global__ __launch_bounds__(256) void predict_kernel(
    const int* __restrict__ el_src, const int* __restrict__ el_dst,
    const ushort_t* __restrict__ hu, const ushort_t* __restrict__ hi,
    float* __restrict__ out)
{
    int l = (blockIdx.x << 2) + (threadIdx.x >> 6);
    if (l >= NLINK) return;
    int lane = threadIdx.x & 63;
    int u = el_src[l];
    int it = el_dst[l];
    float v = bf2f(hu[(size_t)u * 64 + lane]) * bf2f(hi[(size_t)it * 64 + lane]);
#pragma unroll
    for (int o = 32; o >= 1; o >>= 1) v += __shfl_down(v, o, 64);
    if (lane == 0) out[l] = v;
}

extern "C" void kernel_launch(void* const* d_in, const int* in_sizes, int n_in,
                              void* d_out, int out_size, void* d_ws, size_t ws_size,
                              hipStream_t stream) {
    const float* x_user = (const float*)d_in[0];
    const float* x_item = (const float*)d_in[1];
    const int*   src_u  = (const int*)d_in[2];
    const int*   dst_i  = (const int*)d_in[3];
    const int*   el_src = (const int*)d_in[4];
    const int*   el_dst = (const int*)d_in[5];
    const float* Wl_ui1 = (const float*)d_in[6];
    const float* b_ui1  = (const float*)d_in[7];
    const float* Wr_ui1 = (const float*)d_in[8];
    const float* Wl_iu1 = (const float*)d_in[9];
    const float* b_iu1  = (const float*)d_in[10];
    const float* Wr_iu1 = (const float*)d_in[11];
    const float* Wl_ui2 = (const float*)d_in[12];
    const float* b_ui2  = (const float*)d_in[13];
    const float* Wr_ui2 = (const float*)d_in[14];
    const float* Wl_iu2 = (const float*)d_in[15];
    const float* b_iu2  = (const float*)d_in[16];
    const float* Wr_iu2 = (const float*)d_in[17];
    float* out = (float*)d_out;

    // ---- workspace layout (unchanged offsets; bsum slots kept) ----
    int* iw     = (int*)d_ws;
    int* cnt_i  = iw;              // [0, 50000)
    int* cnt_u  = iw + 50000;      // [50000, 150000)
    int* bsum_i = iw + 150000;
    int* bsum_u = iw + 150064;
    int* head_i = iw + 150192;
    int* head_u = iw + 200192;
    int* nbr_i  = iw + 300192;
    int* nbr_u  = iw + 940192;
    char* W8 = (char*)d_ws;
    size_t off = 6320768;
    ushort_t* Bh1u = (ushort_t*)(W8 + off); off += 65536;
    ushort_t* Bl1u = (ushort_t*)(W8 + off); off += 65536;
    ushort_t* Bh1i = (ushort_t*)(W8 + off); off += 65536;
    ushort_t* Bl1i = (ushort_t*)(W8 + off); off += 65536;
    ushort_t* Bh2u = (ushort_t*)(W8 + off); off += 32768;
    ushort_t* Bl2u = (ushort_t*)(W8 + off); off += 32768;
    ushort_t* Bh2i = (ushort_t*)(W8 + off); off += 32768;
    ushort_t* Bl2i = (ushort_t*)(W8 + off); off += 32768;   // off = 6,713,984
    ushort_t* h1_u = (ushort_t*)(W8 + off); off += (size_t)NUSER * 128 * 2;
    ushort_t* h1_i = (ushort_t*)(W8 + off); off += (size_t)NITEM * 128 * 2;
    size_t YB = off;                                        // 45,113,984
    ushort_t* ymsg_u = (ushort_t*)(W8 + YB);
    ushort_t* ymsg_i = (ushort_t*)(W8 + YB + 25600000);
    ushort_t* z_u    = (ushort_t*)(W8 + YB + 38400000);
    ushort_t* z_i    = (ushort_t*)(W8 + YB + 64000000);
    ushort_t* ymsg2_u = (ushort_t*)(W8 + YB);
    ushort_t* ymsg2_i = (ushort_t*)(W8 + YB + 12800000);
    ushort_t* z2_u    = (ushort_t*)(W8 + YB + 19200000);
    ushort_t* z2_i    = (ushort_t*)(W8 + YB + 32000000);
    ushort_t* h2_u    = (ushort_t*)(W8 + YB + 38400000);
    ushort_t* h2_i    = (ushort_t*)(W8 + YB + 51200000);

    // No memset: cnt is written wholesale by countw (window-owner LDS count);
    // head by scan; nbr fully claimed by window fill (sum cnt = E); B by
    // wprep; ymsg/z/h by gemm/gather. No global atomics anywhere.

    // ---- [window degree-count | weight pack] ----
    countw_kernel<<<NWF + NWPREP, 512, 0, stream>>>(
        src_u, dst_i, cnt_u, cnt_i,
        Wl_ui1, Wr_iu1, Wl_iu1, Wr_ui1, Wl_ui2, Wr_iu2, Wl_iu2, Wr_ui2,
        Bh1u, Bl1u, Bh1i, Bl1i, Bh2u, Bl2u, Bh2i, Bl2i);

    // ---- ordered exclusive scan (head = start offsets) ----
    scan1_kernel<<<GI + GU, 256, 0, stream>>>(cnt_i, cnt_u, head_i, head_u, bsum_i, bsum_u);
    scan23_kernel<<<GI + GU, 256, 0, stream>>>(head_i, head_u, bsum_i, bsum_u);

    // ---- [layer-1 GEMM (transform-first) | window-owner CSR fill] ----
    gemmfill_kernel<<<NB1G + NWF, 512, 0, stream>>>(
        x_user, x_item, Bh1u, Bh1i,
        ymsg_u, z_u, ymsg_i, z_i,
        src_u, dst_i, head_i, head_u, nbr_i, nbr_u);

    // ---- layer 1 gather ----
    gather1_kernel<<<(NITEM + NUSER) / 4, 256, 0, stream>>>(
        ymsg_u, ymsg_i, nbr_i, head_i, cnt_i, nbr_u, head_u, cnt_u,
        z_i, z_u, b_ui1, b_iu1, h1_i, h1_u);

    // ---- layer 2 ----
    gemm2_kernel<<<NBG2, 512, 0, stream>>>(
        h1_u, h1_i, Bh2u, Bl2u, Bh2i, Bl2i,
        ymsg2_u, z2_u, ymsg2_i, z2_i);
    gather2_kernel<<<(NITEM + NUSER) / 4, 256, 0, stream>>>(
        ymsg2_u, ymsg2_i, nbr_i, head_i, cnt_i, nbr_u, head_u, cnt_u,
        z2_i, z2_u, b_ui2, b_iu2, h2_i, h2_u);

    // ---- link prediction head ----
    predict_kernel<<<NLINK / 4, 256, 0, stream>>>(el_src, el_dst, h2_u, h2_i, out);
}

// Round 13
// 367.410 us; speedup vs baseline: 2.6528x; 2.6528x over previous
//
#include <hip/hip_runtime.h>

#define NUSER 100000
#define NITEM 50000
#define NEDGE 640000
#define NLINK 200000
#define GI 49     // ceil(NITEM/1024)  scan chunks
#define GU 98     // ceil(NUSER/1024)
#define NB1U 1563 // ceil(NUSER/64)  L1 gemm row-blocks (64 rows/block)
#define NB1I 782  // ceil(NITEM/64)
#define NB1G (2 * (NB1U + NB1I))   // 4690: rowblk-major, cg(2) minor
#define NBU 391   // ceil(NUSER/256)  L2 gemm row-blocks
#define NBI 196   // ceil(NITEM/256)
#define NBG2 (2 * (NBU + NBI))     // 1174
#define FCHUNK 4096
#define FNCH 157  // ceil(NEDGE/4096)
#define FPASS 4   // fill node-range passes
// F0 = F1 = 128, F2 = 64

typedef unsigned int  uint;
typedef unsigned short ushort_t;
typedef __attribute__((ext_vector_type(8))) short bf16x8;
typedef __attribute__((ext_vector_type(4))) float f32x4;
typedef __attribute__((ext_vector_type(4))) uint  u32x4;

__device__ __forceinline__ ushort_t f2bf(float f) {           // RNE f32 -> bf16
    uint u = __float_as_uint(f);
    u += 0x7FFFu + ((u >> 16) & 1u);
    return (ushort_t)(u >> 16);
}
__device__ __forceinline__ float bf2f(ushort_t h) { return __uint_as_float(((uint)h) << 16); }
__device__ __forceinline__ float lo16f(uint u) { return __uint_as_float(u << 16); }
__device__ __forceinline__ float hi16f(uint u) { return __uint_as_float(u & 0xFFFF0000u); }

// ---------------------------------------------------------------------------
// Fused [degree count (global atomics, r6-proven) | weight pack].
// ---------------------------------------------------------------------------
__global__ __launch_bounds__(256) void countw_kernel(
    const int* __restrict__ src, const int* __restrict__ dst,
    int* __restrict__ cnt_u, int* __restrict__ cnt_i,
    const float* __restrict__ Wl0, const float* __restrict__ Wr0,
    const float* __restrict__ Wl1, const float* __restrict__ Wr1,
    const float* __restrict__ Wl2, const float* __restrict__ Wr2,
    const float* __restrict__ Wl3, const float* __restrict__ Wr3,
    ushort_t* __restrict__ Bh0, ushort_t* __restrict__ Bl0,
    ushort_t* __restrict__ Bh1, ushort_t* __restrict__ Bl1,
    ushort_t* __restrict__ Bh2, ushort_t* __restrict__ Bl2,
    ushort_t* __restrict__ Bh3, ushort_t* __restrict__ Bl3)
{
    if (blockIdx.x < 2500) {
        int e = blockIdx.x * 256 + threadIdx.x;
        if (e >= NEDGE) return;
        atomicAdd(&cnt_u[src[e]], 1);
        atomicAdd(&cnt_i[dst[e]], 1);
        return;
    }
    int b = blockIdx.x - 2500;
    const float *Wl, *Wr; ushort_t *Bh, *Bl; int FO, t;
    if (b < 16)      { Wl = Wl0; Wr = Wr0; Bh = Bh0; Bl = Bl0; FO = 128; t = b * 256 + threadIdx.x; }
    else if (b < 32) { Wl = Wl1; Wr = Wr1; Bh = Bh1; Bl = Bl1; FO = 128; t = (b - 16) * 256 + threadIdx.x; }
    else if (b < 40) { Wl = Wl2; Wr = Wr2; Bh = Bh2; Bl = Bl2; FO = 64;  t = (b - 32) * 256 + threadIdx.x; }
    else             { Wl = Wl3; Wr = Wr3; Bh = Bh3; Bl = Bl3; FO = 64;  t = (b - 40) * 256 + threadIdx.x; }
    int lane = t & 63, ks = (t >> 6) & 3, nt = t >> 8;
    int col = nt * 16 + (lane & 15);
    int k0 = ks * 32 + (lane >> 4) * 8;
    const float* W = (col < FO) ? Wl : Wr;
    int cc = (col < FO) ? col : col - FO;
#pragma unroll
    for (int j = 0; j < 8; ++j) {
        float v = W[(size_t)(k0 + j) * FO + cc];
        ushort_t h = f2bf(v);
        Bh[(size_t)t * 8 + j] = h;
        Bl[(size_t)t * 8 + j] = f2bf(v - bf2f(h));
    }
}

// ---------------------------------------------------------------------------
// Ordered exclusive scan (unchanged; head = start offsets, fill converts to end).
// ---------------------------------------------------------------------------
__global__ __launch_bounds__(256) void scan1_kernel(
    const int* __restrict__ cnt_i, const int* __restrict__ cnt_u,
    int* __restrict__ head_i, int* __restrict__ head_u,
    int* __restrict__ bsum_i, int* __restrict__ bsum_u)
{
    __shared__ int sh[256];
    int b = blockIdx.x, t = threadIdx.x;
    const int* cnt; int* head; int* bsum; int n, cb;
    if (b < GI) { cnt = cnt_i; head = head_i; bsum = bsum_i; n = NITEM; cb = b; }
    else        { cnt = cnt_u; head = head_u; bsum = bsum_u; n = NUSER; cb = b - GI; }
    int base = cb * 1024 + t * 4;
    int4 v = {0, 0, 0, 0};
    if (base + 3 < n) v = *(const int4*)(cnt + base);
    else {
        if (base + 0 < n) v.x = cnt[base + 0];
        if (base + 1 < n) v.y = cnt[base + 1];
        if (base + 2 < n) v.z = cnt[base + 2];
    }
    int s = v.x + v.y + v.z + v.w;
    sh[t] = s;
    __syncthreads();
    for (int o = 1; o < 256; o <<= 1) {
        int a = (t >= o) ? sh[t - o] : 0;
        __syncthreads();
        sh[t] += a;
        __syncthreads();
    }
    int excl = sh[t] - s;
    if (t == 255) bsum[cb] = sh[255];
    if (base + 0 < n) head[base + 0] = excl;
    if (base + 1 < n) head[base + 1] = excl + v.x;
    if (base + 2 < n) head[base + 2] = excl + v.x + v.y;
    if (base + 3 < n) head[base + 3] = excl + v.x + v.y + v.z;
}

__global__ __launch_bounds__(256) void scan23_kernel(
    int* __restrict__ head_i, int* __restrict__ head_u,
    const int* __restrict__ bsum_i, const int* __restrict__ bsum_u)
{
    __shared__ int sh[256];
    int b = blockIdx.x, t = threadIdx.x;
    int* head; const int* bsum; int n, cb;
    if (b < GI) { head = head_i; bsum = bsum_i; n = NITEM; cb = b; }
    else        { head = head_u; bsum = bsum_u; n = NUSER; cb = b - GI; }
    sh[t] = (t < cb) ? bsum[t] : 0;
    __syncthreads();
    for (int o = 128; o >= 1; o >>= 1) {
        if (t < o) sh[t] += sh[t + o];
        __syncthreads();
    }
    int add = sh[0];
    int base = cb * 1024 + t * 4;
#pragma unroll
    for (int k = 0; k < 4; ++k)
        if (base + k < n) head[base + k] += add;
}

// ---------------------------------------------------------------------------
// L1 GEMM body v6: 256 thr / 4 waves; block = 64 rows x ONE 128-col group.
// Bh staged in TWO 16KB k-half phases -> LDS 16KB -> up to 8 blocks/CU
// (vs r11's 32KB/512thr = 12.5 waves/CU) -- attacks the measured
// latency-bound regime (occ 39%, MfmaUtil 6%). Numerics identical to r11
// (A hi/lo split, Bh RNE, 2 products, same ks order -> bitwise-same acc).
// C bounced through the same 16KB LDS for full-line 256B/row stores.
// ---------------------------------------------------------------------------
__device__ __forceinline__ void gemm1_body(
    const float* __restrict__ A, const ushort_t* __restrict__ Bcg,
    ushort_t* __restrict__ dstp, int n, int row0, u32x4* __restrict__ bsh)
{
    const int t = threadIdx.x;
    const int lane = t & 63, wv = t >> 6;
    const int lr = lane & 15, lg = lane >> 4;
    const int r0 = row0 + wv * 16 + lr;
    const bool rv = r0 < n;
    const float* arow = A + (size_t)r0 * 128;
    const u32x4* gB = (const u32x4*)Bcg;   // 2048 u32x4 (32KB cg slice)

    f32x4 acc[8];
#pragma unroll
    for (int ct = 0; ct < 8; ++ct) { f32x4 zz = {0.f, 0.f, 0.f, 0.f}; acc[ct] = zz; }

    f32x4 fa, fb;
#define LOAD_A1(KS)                                                            \
    {                                                                          \
        fa = f32x4{0.f, 0.f, 0.f, 0.f}; fb = fa;                               \
        if (rv) {                                                              \
            const f32x4* p = (const f32x4*)(arow + (KS) * 32 + lg * 8);        \
            fa = p[0]; fb = p[1];                                              \
        }                                                                      \
    }

    LOAD_A1(0);
#pragma unroll
    for (int h = 0; h < 2; ++h) {
        if (h) __syncthreads();            // LDS half reused
        // stage k-half h of Bh: local (nt, ksl, lane) <- global (nt, 2h+ksl, lane)
#pragma unroll
        for (int i = 0; i < 4; ++i) {
            int il = i * 256 + t;
            int nt = il >> 7, ksl = (il >> 6) & 1, ln = il & 63;
            bsh[il] = gB[(nt * 4 + h * 2 + ksl) * 64 + ln];
        }
        __syncthreads();

#pragma unroll
        for (int ksl = 0; ksl < 2; ++ksl) {
            int ks = h * 2 + ksl;
            float e0s[4] = {fa[0], fa[2], fb[0], fb[2]};
            float e1s[4] = {fa[1], fa[3], fb[1], fb[3]};
            uint hv[4], lv[4];
#pragma unroll
            for (int j = 0; j < 4; ++j) {
                uint au = __float_as_uint(e0s[j]);
                uint bu = __float_as_uint(e1s[j]);
                uint ah_ = au & 0xFFFF0000u, bh_ = bu & 0xFFFF0000u;
                hv[j] = (au >> 16) | bh_;
                float l0 = e0s[j] - __uint_as_float(ah_);   // exact residual
                float l1 = e1s[j] - __uint_as_float(bh_);
                lv[j] = (__float_as_uint(l0) >> 16) | (__float_as_uint(l1) & 0xFFFF0000u);
            }
            u32x4 hq = {hv[0], hv[1], hv[2], hv[3]};
            u32x4 lq = {lv[0], lv[1], lv[2], lv[3]};
            bf16x8 ahf = __builtin_bit_cast(bf16x8, hq);
            bf16x8 alf = __builtin_bit_cast(bf16x8, lq);
            if (ks < 3) LOAD_A1(ks + 1);   // prefetch next ks under the MFMAs

#pragma unroll
            for (int ct = 0; ct < 8; ++ct) {
                bf16x8 bh = __builtin_bit_cast(bf16x8, bsh[(ct * 2 + ksl) * 64 + lane]);
                acc[ct] = __builtin_amdgcn_mfma_f32_16x16x32_bf16(ahf, bh, acc[ct], 0, 0, 0);
                acc[ct] = __builtin_amdgcn_mfma_f32_16x16x32_bf16(alf, bh, acc[ct], 0, 0, 0);
            }
        }
    }
#undef LOAD_A1

    // ---- C bounce: acc -> LDS (B done) -> coalesced full-line store ----
    __syncthreads();
    ushort_t* cl = (ushort_t*)bsh;     // 64 x 128 bf16 = 16KB, exact fit
#pragma unroll
    for (int ct = 0; ct < 8; ++ct) {
        int col = ct * 16 + lr;        // m89 layout: col=lane&15, row=(lane>>4)*4+r
#pragma unroll
        for (int r = 0; r < 4; ++r)
            cl[(wv * 16 + lg * 4 + r) * 128 + col] = f2bf(acc[ct][r]);
    }
    __syncthreads();
    int row = t >> 2, seg = t & 3;     // 64 rows x 4 segs x 64B
    int grow = row0 + row;
    if (grow < n) {
        const u32x4* s = (const u32x4*)(cl + row * 128) + seg * 4;
        u32x4* d = (u32x4*)(dstp + (size_t)grow * 128) + seg * 4;
        d[0] = s[0]; d[1] = s[1]; d[2] = s[2]; d[3] = s[3];
    }
}

// ---------------------------------------------------------------------------
// Fused [layer-1 GEMM | binned CSR fill (r6-proven global-atomic form)].
// Fill converts head from start->end offsets (gathers use [end-cnt, end)).
// ---------------------------------------------------------------------------
__global__ __launch_bounds__(256) void gemmfill_kernel(
    const float* __restrict__ xu, const float* __restrict__ xi,
    const ushort_t* __restrict__ Bh0, const ushort_t* __restrict__ Bh1,
    ushort_t* __restrict__ y0, ushort_t* __restrict__ z0,
    ushort_t* __restrict__ y1, ushort_t* __restrict__ z1,
    const int* __restrict__ src, const int* __restrict__ dst,
    int* __restrict__ head_i, int* __restrict__ head_u,
    int* __restrict__ nbr_i, int* __restrict__ nbr_u)
{
    if (blockIdx.x >= NB1G) {
        int b = blockIdx.x - NB1G;
        int pass = b / (2 * FNCH);
        int rem  = b % (2 * FNCH);
        int dir  = rem / FNCH;
        int base = (rem % FNCH) * FCHUNK;
        int e_end = min(base + FCHUNK, NEDGE);
        if (dir == 0) {
            int lo = pass * (NITEM / FPASS), hi = lo + NITEM / FPASS;
            for (int e = base + threadIdx.x; e < e_end; e += 256) {
                int d = dst[e];
                if (d >= lo && d < hi) nbr_i[atomicAdd(&head_i[d], 1)] = src[e];
            }
        } else {
            int lo = pass * (NUSER / FPASS), hi = lo + NUSER / FPASS;
            for (int e = base + threadIdx.x; e < e_end; e += 256) {
                int s = src[e];
                if (s >= lo && s < hi) nbr_u[atomicAdd(&head_u[s], 1)] = dst[e];
            }
        }
        return;
    }
    __shared__ u32x4 bsh[1024];   // 16KB (B k-half, then C bounce)
    int bid = blockIdx.x;
    if (bid < 2 * NB1U) {
        int rowblk = bid >> 1, cg = bid & 1;
        gemm1_body(xu, Bh0 + (size_t)cg * 16384, cg ? z0 : y0, NUSER, rowblk * 64, bsh);
    } else {
        int b2 = bid - 2 * NB1U;
        int rowblk = b2 >> 1, cg = b2 & 1;
        gemm1_body(xi, Bh1 + (size_t)cg * 16384, cg ? z1 : y1, NITEM, rowblk * 64, bsh);
    }
}

// ---------------------------------------------------------------------------
// L2 GEMM (r9/r11 verified, unchanged): 256 rows x 64-col group, bf16 A,
// B hi+lo in LDS, 2 products, no k-loop barriers.
// ---------------------------------------------------------------------------
__device__ __forceinline__ void gemm2_body(
    const ushort_t* __restrict__ A,
    const ushort_t* __restrict__ Bh, const ushort_t* __restrict__ Bl,
    ushort_t* __restrict__ dstp, int n, int row0,
    u32x4* __restrict__ bshH, u32x4* __restrict__ bshL)
{
#pragma unroll
    for (int i = 0; i < 2; ++i) {
        int idx = i * 512 + threadIdx.x;
        bshH[idx] = ((const u32x4*)Bh)[idx];
        bshL[idx] = ((const u32x4*)Bl)[idx];
    }
    __syncthreads();

    const int lane = threadIdx.x & 63, wv = threadIdx.x >> 6;
    const int lr = lane & 15, lg = lane >> 4;
    const int wrow0 = row0 + wv * 32;
    const int r0 = wrow0 + lr, r1 = wrow0 + 16 + lr;

    f32x4 acc[2][4];
#pragma unroll
    for (int rt = 0; rt < 2; ++rt)
#pragma unroll
        for (int ct = 0; ct < 4; ++ct) { f32x4 zz = {0.f, 0.f, 0.f, 0.f}; acc[rt][ct] = zz; }

    u32x4 qc[2];
#define LOAD_A2(KS)                                                            \
    {                                                                          \
        int kb = (KS) * 32 + lg * 8;                                           \
        int rows[2] = {r0, r1};                                                \
        _Pragma("unroll")                                                      \
        for (int rt = 0; rt < 2; ++rt) {                                       \
            qc[rt] = u32x4{0u, 0u, 0u, 0u};                                    \
            if (rows[rt] < n)                                                  \
                qc[rt] = *(const u32x4*)(A + (size_t)rows[rt] * 128 + kb);     \
        }                                                                      \
    }

    LOAD_A2(0);
#pragma unroll
    for (int ks = 0; ks < 4; ++ks) {
        bf16x8 ah[2];
#pragma unroll
        for (int rt = 0; rt < 2; ++rt) ah[rt] = __builtin_bit_cast(bf16x8, qc[rt]);
        if (ks < 3) LOAD_A2(ks + 1);

#pragma unroll
        for (int ct = 0; ct < 4; ++ct) {
            bf16x8 bh = __builtin_bit_cast(bf16x8, bshH[(ct * 4 + ks) * 64 + lane]);
            bf16x8 bl = __builtin_bit_cast(bf16x8, bshL[(ct * 4 + ks) * 64 + lane]);
#pragma unroll
            for (int rt = 0; rt < 2; ++rt) {
                acc[rt][ct] = __builtin_amdgcn_mfma_f32_16x16x32_bf16(ah[rt], bh, acc[rt][ct], 0, 0, 0);
                acc[rt][ct] = __builtin_amdgcn_mfma_f32_16x16x32_bf16(ah[rt], bl, acc[rt][ct], 0, 0, 0);
            }
        }
    }
#undef LOAD_A2

#pragma unroll
    for (int rt = 0; rt < 2; ++rt)
#pragma unroll
        for (int ct = 0; ct < 4; ++ct) {
            int cc = ct * 16 + lr;
#pragma unroll
            for (int r = 0; r < 4; ++r) {
                int orow = wrow0 + rt * 16 + lg * 4 + r;
                if (orow < n) dstp[(size_t)orow * 64 + cc] = f2bf(acc[rt][ct][r]);
            }
        }
}

__global__ __launch_bounds__(512) void gemm2_kernel(
    const ushort_t* __restrict__ A0, const ushort_t* __restrict__ A1,
    const ushort_t* __restrict__ Bh0, const ushort_t* __restrict__ Bl0,
    const ushort_t* __restrict__ Bh1, const ushort_t* __restrict__ Bl1,
    ushort_t* __restrict__ y0, ushort_t* __restrict__ z0,
    ushort_t* __restrict__ y1, ushort_t* __restrict__ z1)
{
    __shared__ u32x4 bshH[1024];   // 16KB
    __shared__ u32x4 bshL[1024];   // 16KB
    int bid = blockIdx.x;
    if (bid < 2 * NBU) {
        int rowblk = bid >> 1, cg = bid & 1;
        gemm2_body(A0, Bh0 + (size_t)cg * 8192, Bl0 + (size_t)cg * 8192,
                   cg ? z0 : y0, NUSER, rowblk * 256, bshH, bshL);
    } else {
        int b2 = bid - 2 * NBU;
        int rowblk = b2 >> 1, cg = b2 & 1;
        gemm2_body(A1, Bh1 + (size_t)cg * 8192, Bl1 + (size_t)cg * 8192,
                   cg ? z1 : y1, NITEM, rowblk * 256, bshH, bshL);
    }
}

// ---------------------------------------------------------------------------
// Layer-1 gather + epilogue (r6-style end offsets: slice = [end-cnt, end)).
// ---------------------------------------------------------------------------
__global__ __launch_bounds__(256) void gather1_kernel(
    const ushort_t* __restrict__ ymsg_u, const ushort_t* __restrict__ ymsg_i,
    const int* __restrict__ nbr_i, const int* __restrict__ head_i, const int* __restrict__ cnt_i,
    const int* __restrict__ nbr_u, const int* __restrict__ head_u, const int* __restrict__ cnt_u,
    const ushort_t* __restrict__ z_i, const ushort_t* __restrict__ z_u,
    const float* __restrict__ b_ui, const float* __restrict__ b_iu,
    ushort_t* __restrict__ h1_i, ushort_t* __restrict__ h1_u)
{
    int w = (blockIdx.x << 2) + (threadIdx.x >> 6);
    const ushort_t *ym, *z; const int *nbr, *head, *cnt; const float* bias;
    ushort_t* hout; int node;
    if (w < NITEM) { ym = ymsg_u; nbr = nbr_i; head = head_i; cnt = cnt_i; z = z_i; bias = b_ui; hout = h1_i; node = w; }
    else if (w < NITEM + NUSER) { ym = ymsg_i; nbr = nbr_u; head = head_u; cnt = cnt_u; z = z_u; bias = b_iu; hout = h1_u; node = w - NITEM; }
    else return;
    int lane = threadIdx.x & 63;
    int c = cnt[node], end = head[node];
    int j = end - c;
    const uint* Y = (const uint*)ym;
    float ax = 0.f, ay = 0.f;
    for (; j + 7 < end; j += 8) {
        uint u0 = Y[(size_t)nbr[j + 0] * 64 + lane];
        uint u1 = Y[(size_t)nbr[j + 1] * 64 + lane];
        uint u2 = Y[(size_t)nbr[j + 2] * 64 + lane];
        uint u3 = Y[(size_t)nbr[j + 3] * 64 + lane];
        uint u4 = Y[(size_t)nbr[j + 4] * 64 + lane];
        uint u5 = Y[(size_t)nbr[j + 5] * 64 + lane];
        uint u6 = Y[(size_t)nbr[j + 6] * 64 + lane];
        uint u7 = Y[(size_t)nbr[j + 7] * 64 + lane];
        ax += lo16f(u0) + lo16f(u1) + lo16f(u2) + lo16f(u3)
            + lo16f(u4) + lo16f(u5) + lo16f(u6) + lo16f(u7);
        ay += hi16f(u0) + hi16f(u1) + hi16f(u2) + hi16f(u3)
            + hi16f(u4) + hi16f(u5) + hi16f(u6) + hi16f(u7);
    }
    for (; j + 1 < end; j += 2) {
        uint u0 = Y[(size_t)nbr[j + 0] * 64 + lane];
        uint u1 = Y[(size_t)nbr[j + 1] * 64 + lane];
        ax += lo16f(u0) + lo16f(u1);
        ay += hi16f(u0) + hi16f(u1);
    }
    if (j < end) {
        uint u0 = Y[(size_t)nbr[j] * 64 + lane];
        ax += lo16f(u0); ay += hi16f(u0);
    }
    float m = 1.f / fmaxf((float)c, 1.f);
    uint zu = ((const uint*)z)[(size_t)node * 64 + lane];
    float vx = fmaxf(ax * m + lo16f(zu) + bias[lane * 2], 0.f);
    float vy = fmaxf(ay * m + hi16f(zu) + bias[lane * 2 + 1], 0.f);
    ((uint*)hout)[(size_t)node * 64 + lane] = (uint)f2bf(vx) | ((uint)f2bf(vy) << 16);
}

// ---------------------------------------------------------------------------
// Layer-2 gather + epilogue (end offsets).
// ---------------------------------------------------------------------------
__global__ __launch_bounds__(256) void gather2_kernel(
    const ushort_t* __restrict__ ymsg_u, const ushort_t* __restrict__ ymsg_i,
    const int* __restrict__ nbr_i, const int* __restrict__ head_i, const int* __restrict__ cnt_i,
    const int* __restrict__ nbr_u, const int* __restrict__ head_u, const int* __restrict__ cnt_u,
    const ushort_t* __restrict__ z_i, const ushort_t* __restrict__ z_u,
    const float* __restrict__ b_ui, const float* __restrict__ b_iu,
    ushort_t* __restrict__ h2_i, ushort_t* __restrict__ h2_u)
{
    int w = (blockIdx.x << 2) + (threadIdx.x >> 6);
    const ushort_t *ym, *z; const int *nbr, *head, *cnt; const float* bias;
    ushort_t* hout; int node;
    if (w < NITEM) { ym = ymsg_u; nbr = nbr_i; head = head_i; cnt = cnt_i; z = z_i; bias = b_ui; hout = h2_i; node = w; }
    else if (w < NITEM + NUSER) { ym = ymsg_i; nbr = nbr_u; head = head_u; cnt = cnt_u; z = z_u; bias = b_iu; hout = h2_u; node = w - NITEM; }
    else return;
    int lane = threadIdx.x & 63;
    int c = cnt[node], end = head[node];
    int j = end - c;
    float a = 0.f;
    for (; j + 7 < end; j += 8) {
        a += bf2f(ym[(size_t)nbr[j + 0] * 64 + lane]) + bf2f(ym[(size_t)nbr[j + 1] * 64 + lane])
           + bf2f(ym[(size_t)nbr[j + 2] * 64 + lane]) + bf2f(ym[(size_t)nbr[j + 3] * 64 + lane])
           + bf2f(ym[(size_t)nbr[j + 4] * 64 + lane]) + bf2f(ym[(size_t)nbr[j + 5] * 64 + lane])
           + bf2f(ym[(size_t)nbr[j + 6] * 64 + lane]) + bf2f(ym[(size_t)nbr[j + 7] * 64 + lane]);
    }
    for (; j + 1 < end; j += 2)
        a += bf2f(ym[(size_t)nbr[j] * 64 + lane]) + bf2f(ym[(size_t)nbr[j + 1] * 64 + lane]);
    if (j < end) a += bf2f(ym[(size_t)nbr[j] * 64 + lane]);
    float m = 1.f / fmaxf((float)c, 1.f);
    float v = a * m + bf2f(z[(size_t)node * 64 + lane]) + bias[lane];
    hout[(size_t)node * 64 + lane] = f2bf(v);
}

// ---------------------------------------------------------------------------
// Link head (unchanged).
// ---------------------------------------------------------------------------
__global__ __launch_bounds__(256) void predict_kernel(
    const int* __restrict__ el_src, const int* __restrict__ el_dst,
    const ushort_t* __restrict__ hu, const ushort_t* __restrict__ hi,
    float* __restrict__ out)
{
    int l = (blockIdx.x << 2) + (threadIdx.x >> 6);
    if (l >= NLINK) return;
    int lane = threadIdx.x & 63;
    int u = el_src[l];
    int it = el_dst[l];
    float v = bf2f(hu[(size_t)u * 64 + lane]) * bf2f(hi[(size_t)it * 64 + lane]);
#pragma unroll
    for (int o = 32; o >= 1; o >>= 1) v += __shfl_down(v, o, 64);
    if (lane == 0) out[l] = v;
}

extern "C" void kernel_launch(void* const* d_in, const int* in_sizes, int n_in,
                              void* d_out, int out_size, void* d_ws, size_t ws_size,
                              hipStream_t stream) {
    const float* x_user = (const float*)d_in[0];
    const float* x_item = (const float*)d_in[1];
    const int*   src_u  = (const int*)d_in[2];
    const int*   dst_i  = (const int*)d_in[3];
    const int*   el_src = (const int*)d_in[4];
    const int*   el_dst = (const int*)d_in[5];
    const float* Wl_ui1 = (const float*)d_in[6];
    const float* b_ui1  = (const float*)d_in[7];
    const float* Wr_ui1 = (const float*)d_in[8];
    const float* Wl_iu1 = (const float*)d_in[9];
    const float* b_iu1  = (const float*)d_in[10];
    const float* Wr_iu1 = (const float*)d_in[11];
    const float* Wl_ui2 = (const float*)d_in[12];
    const float* b_ui2  = (const float*)d_in[13];
    const float* Wr_ui2 = (const float*)d_in[14];
    const float* Wl_iu2 = (const float*)d_in[15];
    const float* b_iu2  = (const float*)d_in[16];
    const float* Wr_iu2 = (const float*)d_in[17];
    float* out = (float*)d_out;

    // ---- workspace layout (r11 offsets) ----
    int* iw     = (int*)d_ws;
    int* cnt_i  = iw;              // [0, 50000)
    int* cnt_u  = iw + 50000;      // [50000, 150000)
    int* bsum_i = iw + 150000;
    int* bsum_u = iw + 150064;
    int* head_i = iw + 150192;
    int* head_u = iw + 200192;
    int* nbr_i  = iw + 300192;
    int* nbr_u  = iw + 940192;
    char* W8 = (char*)d_ws;
    size_t off = 6320768;
    ushort_t* Bh1u = (ushort_t*)(W8 + off); off += 65536;
    ushort_t* Bl1u = (ushort_t*)(W8 + off); off += 65536;
    ushort_t* Bh1i = (ushort_t*)(W8 + off); off += 65536;
    ushort_t* Bl1i = (ushort_t*)(W8 + off); off += 65536;
    ushort_t* Bh2u = (ushort_t*)(W8 + off); off += 32768;
    ushort_t* Bl2u = (ushort_t*)(W8 + off); off += 32768;
    ushort_t* Bh2i = (ushort_t*)(W8 + off); off += 32768;
    ushort_t* Bl2i = (ushort_t*)(W8 + off); off += 32768;   // off = 6,713,984
    ushort_t* h1_u = (ushort_t*)(W8 + off); off += (size_t)NUSER * 128 * 2;
    ushort_t* h1_i = (ushort_t*)(W8 + off); off += (size_t)NITEM * 128 * 2;
    size_t YB = off;                                        // 45,113,984
    ushort_t* ymsg_u = (ushort_t*)(W8 + YB);
    ushort_t* ymsg_i = (ushort_t*)(W8 + YB + 25600000);
    ushort_t* z_u    = (ushort_t*)(W8 + YB + 38400000);
    ushort_t* z_i    = (ushort_t*)(W8 + YB + 64000000);
    ushort_t* ymsg2_u = (ushort_t*)(W8 + YB);
    ushort_t* ymsg2_i = (ushort_t*)(W8 + YB + 12800000);
    ushort_t* z2_u    = (ushort_t*)(W8 + YB + 19200000);
    ushort_t* z2_i    = (ushort_t*)(W8 + YB + 32000000);
    ushort_t* h2_u    = (ushort_t*)(W8 + YB + 38400000);
    ushort_t* h2_i    = (ushort_t*)(W8 + YB + 51200000);

    // Zero ONLY cnt (atomic-incremented); everything else written-before-read.
    hipMemsetAsync(d_ws, 0, 150000 * sizeof(int), stream);

    // ---- [degree count | weight pack] ----
    countw_kernel<<<2548, 256, 0, stream>>>(
        src_u, dst_i, cnt_u, cnt_i,
        Wl_ui1, Wr_iu1, Wl_iu1, Wr_ui1, Wl_ui2, Wr_iu2, Wl_iu2, Wr_ui2,
        Bh1u, Bl1u, Bh1i, Bl1i, Bh2u, Bl2u, Bh2i, Bl2i);

    // ---- ordered exclusive scan ----
    scan1_kernel<<<GI + GU, 256, 0, stream>>>(cnt_i, cnt_u, head_i, head_u, bsum_i, bsum_u);
    scan23_kernel<<<GI + GU, 256, 0, stream>>>(head_i, head_u, bsum_i, bsum_u);

    // ---- [layer-1 GEMM (transform-first, 64-row blocks) | binned fill] ----
    gemmfill_kernel<<<NB1G + FPASS * 2 * FNCH, 256, 0, stream>>>(
        x_user, x_item, Bh1u, Bh1i,
        ymsg_u, z_u, ymsg_i, z_i,
        src_u, dst_i, head_i, head_u, nbr_i, nbr_u);

    // ---- layer 1 gather ----
    gather1_kernel<<<(NITEM + NUSER) / 4, 256, 0, stream>>>(
        ymsg_u, ymsg_i, nbr_i, head_i, cnt_i, nbr_u, head_u, cnt_u,
        z_i, z_u, b_ui1, b_iu1, h1_i, h1_u);

    // ---- layer 2 ----
    gemm2_kernel<<<NBG2, 512, 0, stream>>>(
        h1_u, h1_i, Bh2u, Bl2u, Bh2i, Bl2i,
        ymsg2_u, z2_u, ymsg2_i, z2_i);
    gather2_kernel<<<(NITEM + NUSER) / 4, 256, 0, stream>>>(
        ymsg2_u, ymsg2_i, nbr_i, head_i, cnt_i, nbr_u, head_u, cnt_u,
        z2_i, z2_u, b_ui2, b_iu2, h2_i, h2_u);

    // ---- link prediction head ----
    predict_kernel<<<NLINK / 4, 256, 0, stream>>>(el_src, el_dst, h2_u, h2_i, out);
}

// Round 14
// 361.515 us; speedup vs baseline: 2.6960x; 1.0163x over previous
//
#include <hip/hip_runtime.h>

#define NUSER 100000
#define NITEM 50000
#define NEDGE 640000
#define NLINK 200000
#define GI 49     // ceil(NITEM/1024)  scan chunks
#define GU 98     // ceil(NUSER/1024)
#define NB1U 782  // ceil(NUSER/128)  L1 gemm row-blocks (128 rows/block)
#define NB1I 391  // ceil(NITEM/128)
#define NB1G (2 * (NB1U + NB1I))   // 2346: rowblk-major, cg(2) minor
#define NBU 391   // ceil(NUSER/256)  L2 gemm row-blocks
#define NBI 196   // ceil(NITEM/256)
#define NBG2 (2 * (NBU + NBI))     // 1174
#define FCHUNK 2048
#define FNCH 313  // ceil(NEDGE/2048)
#define FPASS 8   // fill node-range passes (r6-proven: many small fill blocks)
#define NFILL (FPASS * 2 * FNCH)   // 5008 fill blocks, launched FIRST
// F0 = F1 = 128, F2 = 64

typedef unsigned int  uint;
typedef unsigned short ushort_t;
typedef __attribute__((ext_vector_type(8))) short bf16x8;
typedef __attribute__((ext_vector_type(4))) float f32x4;
typedef __attribute__((ext_vector_type(4))) uint  u32x4;

__device__ __forceinline__ ushort_t f2bf(float f) {           // RNE f32 -> bf16
    uint u = __float_as_uint(f);
    u += 0x7FFFu + ((u >> 16) & 1u);
    return (ushort_t)(u >> 16);
}
__device__ __forceinline__ float bf2f(ushort_t h) { return __uint_as_float(((uint)h) << 16); }
__device__ __forceinline__ float lo16f(uint u) { return __uint_as_float(u << 16); }
__device__ __forceinline__ float hi16f(uint u) { return __uint_as_float(u & 0xFFFF0000u); }

// ---------------------------------------------------------------------------
// Fused [degree count (global atomics) | weight pack] (r6-proven).
// ---------------------------------------------------------------------------
__global__ __launch_bounds__(256) void countw_kernel(
    const int* __restrict__ src, const int* __restrict__ dst,
    int* __restrict__ cnt_u, int* __restrict__ cnt_i,
    const float* __restrict__ Wl0, const float* __restrict__ Wr0,
    const float* __restrict__ Wl1, const float* __restrict__ Wr1,
    const float* __restrict__ Wl2, const float* __restrict__ Wr2,
    const float* __restrict__ Wl3, const float* __restrict__ Wr3,
    ushort_t* __restrict__ Bh0, ushort_t* __restrict__ Bl0,
    ushort_t* __restrict__ Bh1, ushort_t* __restrict__ Bl1,
    ushort_t* __restrict__ Bh2, ushort_t* __restrict__ Bl2,
    ushort_t* __restrict__ Bh3, ushort_t* __restrict__ Bl3)
{
    if (blockIdx.x < 2500) {
        int e = blockIdx.x * 256 + threadIdx.x;
        if (e >= NEDGE) return;
        atomicAdd(&cnt_u[src[e]], 1);
        atomicAdd(&cnt_i[dst[e]], 1);
        return;
    }
    int b = blockIdx.x - 2500;
    const float *Wl, *Wr; ushort_t *Bh, *Bl; int FO, t;
    if (b < 16)      { Wl = Wl0; Wr = Wr0; Bh = Bh0; Bl = Bl0; FO = 128; t = b * 256 + threadIdx.x; }
    else if (b < 32) { Wl = Wl1; Wr = Wr1; Bh = Bh1; Bl = Bl1; FO = 128; t = (b - 16) * 256 + threadIdx.x; }
    else if (b < 40) { Wl = Wl2; Wr = Wr2; Bh = Bh2; Bl = Bl2; FO = 64;  t = (b - 32) * 256 + threadIdx.x; }
    else             { Wl = Wl3; Wr = Wr3; Bh = Bh3; Bl = Bl3; FO = 64;  t = (b - 40) * 256 + threadIdx.x; }
    int lane = t & 63, ks = (t >> 6) & 3, nt = t >> 8;
    int col = nt * 16 + (lane & 15);
    int k0 = ks * 32 + (lane >> 4) * 8;
    const float* W = (col < FO) ? Wl : Wr;
    int cc = (col < FO) ? col : col - FO;
#pragma unroll
    for (int j = 0; j < 8; ++j) {
        float v = W[(size_t)(k0 + j) * FO + cc];
        ushort_t h = f2bf(v);
        Bh[(size_t)t * 8 + j] = h;
        Bl[(size_t)t * 8 + j] = f2bf(v - bf2f(h));
    }
}

// ---------------------------------------------------------------------------
// Ordered exclusive scan (unchanged; head = start offsets, fill -> end).
// ---------------------------------------------------------------------------
__global__ __launch_bounds__(256) void scan1_kernel(
    const int* __restrict__ cnt_i, const int* __restrict__ cnt_u,
    int* __restrict__ head_i, int* __restrict__ head_u,
    int* __restrict__ bsum_i, int* __restrict__ bsum_u)
{
    __shared__ int sh[256];
    int b = blockIdx.x, t = threadIdx.x;
    const int* cnt; int* head; int* bsum; int n, cb;
    if (b < GI) { cnt = cnt_i; head = head_i; bsum = bsum_i; n = NITEM; cb = b; }
    else        { cnt = cnt_u; head = head_u; bsum = bsum_u; n = NUSER; cb = b - GI; }
    int base = cb * 1024 + t * 4;
    int4 v = {0, 0, 0, 0};
    if (base + 3 < n) v = *(const int4*)(cnt + base);
    else {
        if (base + 0 < n) v.x = cnt[base + 0];
        if (base + 1 < n) v.y = cnt[base + 1];
        if (base + 2 < n) v.z = cnt[base + 2];
    }
    int s = v.x + v.y + v.z + v.w;
    sh[t] = s;
    __syncthreads();
    for (int o = 1; o < 256; o <<= 1) {
        int a = (t >= o) ? sh[t - o] : 0;
        __syncthreads();
        sh[t] += a;
        __syncthreads();
    }
    int excl = sh[t] - s;
    if (t == 255) bsum[cb] = sh[255];
    if (base + 0 < n) head[base + 0] = excl;
    if (base + 1 < n) head[base + 1] = excl + v.x;
    if (base + 2 < n) head[base + 2] = excl + v.x + v.y;
    if (base + 3 < n) head[base + 3] = excl + v.x + v.y + v.z;
}

__global__ __launch_bounds__(256) void scan23_kernel(
    int* __restrict__ head_i, int* __restrict__ head_u,
    const int* __restrict__ bsum_i, const int* __restrict__ bsum_u)
{
    __shared__ int sh[256];
    int b = blockIdx.x, t = threadIdx.x;
    int* head; const int* bsum; int n, cb;
    if (b < GI) { head = head_i; bsum = bsum_i; n = NITEM; cb = b; }
    else        { head = head_u; bsum = bsum_u; n = NUSER; cb = b - GI; }
    sh[t] = (t < cb) ? bsum[t] : 0;
    __syncthreads();
    for (int o = 128; o >= 1; o >>= 1) {
        if (t < o) sh[t] += sh[t + o];
        __syncthreads();
    }
    int add = sh[0];
    int base = cb * 1024 + t * 4;
#pragma unroll
    for (int k = 0; k < 4; ++k)
        if (base + k < n) head[base + k] += add;
}

// ---------------------------------------------------------------------------
// L1 GEMM body (r11, verified 122us config): block = 128 rows x ONE 128-col
// group. A-split-only numerics (2 MFMA products), Bh LDS-resident (32KB),
// C bounced through LDS for full-line 256B/row coalesced stores.
// ---------------------------------------------------------------------------
__device__ __forceinline__ void gemm1_body(
    const float* __restrict__ A, const ushort_t* __restrict__ Bcg,
    ushort_t* __restrict__ dstp, int n, int row0, u32x4* __restrict__ bsh)
{
#pragma unroll
    for (int i = 0; i < 4; ++i)
        bsh[i * 512 + threadIdx.x] = ((const u32x4*)Bcg)[i * 512 + threadIdx.x];
    __syncthreads();

    const int lane = threadIdx.x & 63, wv = threadIdx.x >> 6;
    const int lr = lane & 15, lg = lane >> 4;
    const int r0 = row0 + wv * 16 + lr;
    const bool rv = r0 < n;
    const float* arow = A + (size_t)r0 * 128;

    f32x4 acc[8];
#pragma unroll
    for (int ct = 0; ct < 8; ++ct) { f32x4 zz = {0.f, 0.f, 0.f, 0.f}; acc[ct] = zz; }

    f32x4 fa, fb;
#define LOAD_A1(KS)                                                            \
    {                                                                          \
        fa = f32x4{0.f, 0.f, 0.f, 0.f}; fb = fa;                               \
        if (rv) {                                                              \
            const f32x4* p = (const f32x4*)(arow + (KS) * 32 + lg * 8);        \
            fa = p[0]; fb = p[1];                                              \
        }                                                                      \
    }

    LOAD_A1(0);
#pragma unroll
    for (int ks = 0; ks < 4; ++ks) {
        float e0s[4] = {fa[0], fa[2], fb[0], fb[2]};
        float e1s[4] = {fa[1], fa[3], fb[1], fb[3]};
        uint hv[4], lv[4];
#pragma unroll
        for (int j = 0; j < 4; ++j) {
            uint au = __float_as_uint(e0s[j]);
            uint bu = __float_as_uint(e1s[j]);
            uint ah_ = au & 0xFFFF0000u, bh_ = bu & 0xFFFF0000u;
            hv[j] = (au >> 16) | bh_;
            float l0 = e0s[j] - __uint_as_float(ah_);   // exact residual
            float l1 = e1s[j] - __uint_as_float(bh_);
            lv[j] = (__float_as_uint(l0) >> 16) | (__float_as_uint(l1) & 0xFFFF0000u);
        }
        u32x4 hq = {hv[0], hv[1], hv[2], hv[3]};
        u32x4 lq = {lv[0], lv[1], lv[2], lv[3]};
        bf16x8 ahf = __builtin_bit_cast(bf16x8, hq);
        bf16x8 alf = __builtin_bit_cast(bf16x8, lq);
        if (ks < 3) LOAD_A1(ks + 1);   // prefetch next ks under the MFMAs

#pragma unroll
        for (int ct = 0; ct < 8; ++ct) {
            bf16x8 bh = __builtin_bit_cast(bf16x8, bsh[(ct * 4 + ks) * 64 + lane]);
            acc[ct] = __builtin_amdgcn_mfma_f32_16x16x32_bf16(ahf, bh, acc[ct], 0, 0, 0);
            acc[ct] = __builtin_amdgcn_mfma_f32_16x16x32_bf16(alf, bh, acc[ct], 0, 0, 0);
        }
    }
#undef LOAD_A1

    // ---- C bounce: acc -> LDS (B no longer needed) -> coalesced store ----
    __syncthreads();
    ushort_t* cl = (ushort_t*)bsh;     // 128 x 128 bf16 = 32KB, exact fit
#pragma unroll
    for (int ct = 0; ct < 8; ++ct) {
        int col = ct * 16 + lr;        // m89 layout: col=lane&15, row=(lane>>4)*4+r
#pragma unroll
        for (int r = 0; r < 4; ++r)
            cl[(wv * 16 + lg * 4 + r) * 128 + col] = f2bf(acc[ct][r]);
    }
    __syncthreads();
    int row = threadIdx.x >> 2, seg = threadIdx.x & 3;
    int grow = row0 + row;
    if (grow < n) {
        const u32x4* s = (const u32x4*)(cl + row * 128) + seg * 4;
        u32x4* d = (u32x4*)(dstp + (size_t)grow * 128) + seg * 4;
        d[0] = s[0]; d[1] = s[1]; d[2] = s[2]; d[3] = s[3];   // 64B/thread
    }
}

// ---------------------------------------------------------------------------
// Fused [binned CSR fill (FIRST: overlaps under gemm) | layer-1 GEMM].
// Fill blocks [0, NFILL): many small blocks (r6-proven shape) so the
// atomic-latency-bound fill overlaps the gemm blocks that backfill behind
// it, instead of forming a low-occupancy tail. Converts head start->end.
// ---------------------------------------------------------------------------
__global__ __launch_bounds__(512) void gemmfill_kernel(
    const float* __restrict__ xu, const float* __restrict__ xi,
    const ushort_t* __restrict__ Bh0, const ushort_t* __restrict__ Bh1,
    ushort_t* __restrict__ y0, ushort_t* __restrict__ z0,
    ushort_t* __restrict__ y1, ushort_t* __restrict__ z1,
    const int* __restrict__ src, const int* __restrict__ dst,
    int* __restrict__ head_i, int* __restrict__ head_u,
    int* __restrict__ nbr_i, int* __restrict__ nbr_u)
{
    if (blockIdx.x < NFILL) {
        int b = blockIdx.x;
        int pass = b / (2 * FNCH);
        int rem  = b % (2 * FNCH);
        int dir  = rem / FNCH;
        int base = (rem % FNCH) * FCHUNK;
        int e_end = min(base + FCHUNK, NEDGE);
        if (dir == 0) {
            int lo = pass * (NITEM / FPASS), hi = lo + NITEM / FPASS;
            for (int e = base + threadIdx.x; e < e_end; e += 512) {
                int d = dst[e];
                if (d >= lo && d < hi) nbr_i[atomicAdd(&head_i[d], 1)] = src[e];
            }
        } else {
            int lo = pass * (NUSER / FPASS), hi = lo + NUSER / FPASS;
            for (int e = base + threadIdx.x; e < e_end; e += 512) {
                int s = src[e];
                if (s >= lo && s < hi) nbr_u[atomicAdd(&head_u[s], 1)] = dst[e];
            }
        }
        return;
    }
    __shared__ u32x4 bsh[2048];   // 32KB (Bh slice, then C bounce)
    int bid = blockIdx.x - NFILL;
    if (bid < 2 * NB1U) {
        int rowblk = bid >> 1, cg = bid & 1;
        gemm1_body(xu, Bh0 + (size_t)cg * 16384, cg ? z0 : y0, NUSER, rowblk * 128, bsh);
    } else {
        int b2 = bid - 2 * NB1U;
        int rowblk = b2 >> 1, cg = b2 & 1;
        gemm1_body(xi, Bh1 + (size_t)cg * 16384, cg ? z1 : y1, NITEM, rowblk * 128, bsh);
    }
}

// ---------------------------------------------------------------------------
// L2 GEMM (r9/r11 verified, unchanged).
// ---------------------------------------------------------------------------
__device__ __forceinline__ void gemm2_body(
    const ushort_t* __restrict__ A,
    const ushort_t* __restrict__ Bh, const ushort_t* __restrict__ Bl,
    ushort_t* __restrict__ dstp, int n, int row0,
    u32x4* __restrict__ bshH, u32x4* __restrict__ bshL)
{
#pragma unroll
    for (int i = 0; i < 2; ++i) {
        int idx = i * 512 + threadIdx.x;
        bshH[idx] = ((const u32x4*)Bh)[idx];
        bshL[idx] = ((const u32x4*)Bl)[idx];
    }
    __syncthreads();

    const int lane = threadIdx.x & 63, wv = threadIdx.x >> 6;
    const int lr = lane & 15, lg = lane >> 4;
    const int wrow0 = row0 + wv * 32;
    const int r0 = wrow0 + lr, r1 = wrow0 + 16 + lr;

    f32x4 acc[2][4];
#pragma unroll
    for (int rt = 0; rt < 2; ++rt)
#pragma unroll
        for (int ct = 0; ct < 4; ++ct) { f32x4 zz = {0.f, 0.f, 0.f, 0.f}; acc[rt][ct] = zz; }

    u32x4 qc[2];
#define LOAD_A2(KS)                                                            \
    {                                                                          \
        int kb = (KS) * 32 + lg * 8;                                           \
        int rows[2] = {r0, r1};                                                \
        _Pragma("unroll")                                                      \
        for (int rt = 0; rt < 2; ++rt) {                                       \
            qc[rt] = u32x4{0u, 0u, 0u, 0u};                                    \
            if (rows[rt] < n)                                                  \
                qc[rt] = *(const u32x4*)(A + (size_t)rows[rt] * 128 + kb);     \
        }                                                                      \
    }

    LOAD_A2(0);
#pragma unroll
    for (int ks = 0; ks < 4; ++ks) {
        bf16x8 ah[2];
#pragma unroll
        for (int rt = 0; rt < 2; ++rt) ah[rt] = __builtin_bit_cast(bf16x8, qc[rt]);
        if (ks < 3) LOAD_A2(ks + 1);

#pragma unroll
        for (int ct = 0; ct < 4; ++ct) {
            bf16x8 bh = __builtin_bit_cast(bf16x8, bshH[(ct * 4 + ks) * 64 + lane]);
            bf16x8 bl = __builtin_bit_cast(bf16x8, bshL[(ct * 4 + ks) * 64 + lane]);
#pragma unroll
            for (int rt = 0; rt < 2; ++rt) {
                acc[rt][ct] = __builtin_amdgcn_mfma_f32_16x16x32_bf16(ah[rt], bh, acc[rt][ct], 0, 0, 0);
                acc[rt][ct] = __builtin_amdgcn_mfma_f32_16x16x32_bf16(ah[rt], bl, acc[rt][ct], 0, 0, 0);
            }
        }
    }
#undef LOAD_A2

#pragma unroll
    for (int rt = 0; rt < 2; ++rt)
#pragma unroll
        for (int ct = 0; ct < 4; ++ct) {
            int cc = ct * 16 + lr;
#pragma unroll
            for (int r = 0; r < 4; ++r) {
                int orow = wrow0 + rt * 16 + lg * 4 + r;
                if (orow < n) dstp[(size_t)orow * 64 + cc] = f2bf(acc[rt][ct][r]);
            }
        }
}

__global__ __launch_bounds__(512) void gemm2_kernel(
    const ushort_t* __restrict__ A0, const ushort_t* __restrict__ A1,
    const ushort_t* __restrict__ Bh0, const ushort_t* __restrict__ Bl0,
    const ushort_t* __restrict__ Bh1, const ushort_t* __restrict__ Bl1,
    ushort_t* __restrict__ y0, ushort_t* __restrict__ z0,
    ushort_t* __restrict__ y1, ushort_t* __restrict__ z1)
{
    __shared__ u32x4 bshH[1024];   // 16KB
    __shared__ u32x4 bshL[1024];   // 16KB
    int bid = blockIdx.x;
    if (bid < 2 * NBU) {
        int rowblk = bid >> 1, cg = bid & 1;
        gemm2_body(A0, Bh0 + (size_t)cg * 8192, Bl0 + (size_t)cg * 8192,
                   cg ? z0 : y0, NUSER, rowblk * 256, bshH, bshL);
    } else {
        int b2 = bid - 2 * NBU;
        int rowblk = b2 >> 1, cg = b2 & 1;
        gemm2_body(A1, Bh1 + (size_t)cg * 8192, Bl1 + (size_t)cg * 8192,
                   cg ? z1 : y1, NITEM, rowblk * 256, bshH, bshL);
    }
}

// ---------------------------------------------------------------------------
// Layer-1 gather + epilogue (end offsets: slice = [end-cnt, end)).
// ---------------------------------------------------------------------------
__global__ __launch_bounds__(256) void gather1_kernel(
    const ushort_t* __restrict__ ymsg_u, const ushort_t* __restrict__ ymsg_i,
    const int* __restrict__ nbr_i, const int* __restrict__ head_i, const int* __restrict__ cnt_i,
    const int* __restrict__ nbr_u, const int* __restrict__ head_u, const int* __restrict__ cnt_u,
    const ushort_t* __restrict__ z_i, const ushort_t* __restrict__ z_u,
    const float* __restrict__ b_ui, const float* __restrict__ b_iu,
    ushort_t* __restrict__ h1_i, ushort_t* __restrict__ h1_u)
{
    int w = (blockIdx.x << 2) + (threadIdx.x >> 6);
    const ushort_t *ym, *z; const int *nbr, *head, *cnt; const float* bias;
    ushort_t* hout; int node;
    if (w < NITEM) { ym = ymsg_u; nbr = nbr_i; head = head_i; cnt = cnt_i; z = z_i; bias = b_ui; hout = h1_i; node = w; }
    else if (w < NITEM + NUSER) { ym = ymsg_i; nbr = nbr_u; head = head_u; cnt = cnt_u; z = z_u; bias = b_iu; hout = h1_u; node = w - NITEM; }
    else return;
    int lane = threadIdx.x & 63;
    int c = cnt[node], end = head[node];
    int j = end - c;
    const uint* Y = (const uint*)ym;
    float ax = 0.f, ay = 0.f;
    for (; j + 7 < end; j += 8) {
        uint u0 = Y[(size_t)nbr[j + 0] * 64 + lane];
        uint u1 = Y[(size_t)nbr[j + 1] * 64 + lane];
        uint u2 = Y[(size_t)nbr[j + 2] * 64 + lane];
        uint u3 = Y[(size_t)nbr[j + 3] * 64 + lane];
        uint u4 = Y[(size_t)nbr[j + 4] * 64 + lane];
        uint u5 = Y[(size_t)nbr[j + 5] * 64 + lane];
        uint u6 = Y[(size_t)nbr[j + 6] * 64 + lane];
        uint u7 = Y[(size_t)nbr[j + 7] * 64 + lane];
        ax += lo16f(u0) + lo16f(u1) + lo16f(u2) + lo16f(u3)
            + lo16f(u4) + lo16f(u5) + lo16f(u6) + lo16f(u7);
        ay += hi16f(u0) + hi16f(u1) + hi16f(u2) + hi16f(u3)
            + hi16f(u4) + hi16f(u5) + hi16f(u6) + hi16f(u7);
    }
    for (; j + 1 < end; j += 2) {
        uint u0 = Y[(size_t)nbr[j + 0] * 64 + lane];
        uint u1 = Y[(size_t)nbr[j + 1] * 64 + lane];
        ax += lo16f(u0) + lo16f(u1);
        ay += hi16f(u0) + hi16f(u1);
    }
    if (j < end) {
        uint u0 = Y[(size_t)nbr[j] * 64 + lane];
        ax += lo16f(u0); ay += hi16f(u0);
    }
    float m = 1.f / fmaxf((float)c, 1.f);
    uint zu = ((const uint*)z)[(size_t)node * 64 + lane];
    float vx = fmaxf(ax * m + lo16f(zu) + bias[lane * 2], 0.f);
    float vy = fmaxf(ay * m + hi16f(zu) + bias[lane * 2 + 1], 0.f);
    ((uint*)hout)[(size_t)node * 64 + lane] = (uint)f2bf(vx) | ((uint)f2bf(vy) << 16);
}

// ---------------------------------------------------------------------------
// Layer-2 gather + epilogue (end offsets).
// ---------------------------------------------------------------------------
__global__ __launch_bounds__(256) void gather2_kernel(
    const ushort_t* __restrict__ ymsg_u, const ushort_t* __restrict__ ymsg_i,
    const int* __restrict__ nbr_i, const int* __restrict__ head_i, const int* __restrict__ cnt_i,
    const int* __restrict__ nbr_u, const int* __restrict__ head_u, const int* __restrict__ cnt_u,
    const ushort_t* __restrict__ z_i, const ushort_t* __restrict__ z_u,
    const float* __restrict__ b_ui, const float* __restrict__ b_iu,
    ushort_t* __restrict__ h2_i, ushort_t* __restrict__ h2_u)
{
    int w = (blockIdx.x << 2) + (threadIdx.x >> 6);
    const ushort_t *ym, *z; const int *nbr, *head, *cnt; const float* bias;
    ushort_t* hout; int node;
    if (w < NITEM) { ym = ymsg_u; nbr = nbr_i; head = head_i; cnt = cnt_i; z = z_i; bias = b_ui; hout = h2_i; node = w; }
    else if (w < NITEM + NUSER) { ym = ymsg_i; nbr = nbr_u; head = head_u; cnt = cnt_u; z = z_u; bias = b_iu; hout = h2_u; node = w - NITEM; }
    else return;
    int lane = threadIdx.x & 63;
    int c = cnt[node], end = head[node];
    int j = end - c;
    float a = 0.f;
    for (; j + 7 < end; j += 8) {
        a += bf2f(ym[(size_t)nbr[j + 0] * 64 + lane]) + bf2f(ym[(size_t)nbr[j + 1] * 64 + lane])
           + bf2f(ym[(size_t)nbr[j + 2] * 64 + lane]) + bf2f(ym[(size_t)nbr[j + 3] * 64 + lane])
           + bf2f(ym[(size_t)nbr[j + 4] * 64 + lane]) + bf2f(ym[(size_t)nbr[j + 5] * 64 + lane])
           + bf2f(ym[(size_t)nbr[j + 6] * 64 + lane]) + bf2f(ym[(size_t)nbr[j + 7] * 64 + lane]);
    }
    for (; j + 1 < end; j += 2)
        a += bf2f(ym[(size_t)nbr[j] * 64 + lane]) + bf2f(ym[(size_t)nbr[j + 1] * 64 + lane]);
    if (j < end) a += bf2f(ym[(size_t)nbr[j] * 64 + lane]);
    float m = 1.f / fmaxf((float)c, 1.f);
    float v = a * m + bf2f(z[(size_t)node * 64 + lane]) + bias[lane];
    hout[(size_t)node * 64 + lane] = f2bf(v);
}

// ---------------------------------------------------------------------------
// Link head (unchanged).
// ---------------------------------------------------------------------------
__global__ __launch_bounds__(256) void predict_kernel(
    const int* __restrict__ el_src, const int* __restrict__ el_dst,
    const ushort_t* __restrict__ hu, const ushort_t* __restrict__ hi,
    float* __restrict__ out)
{
    int l = (blockIdx.x << 2) + (threadIdx.x >> 6);
    if (l >= NLINK) return;
    int lane = threadIdx.x & 63;
    int u = el_src[l];
    int it = el_dst[l];
    float v = bf2f(hu[(size_t)u * 64 + lane]) * bf2f(hi[(size_t)it * 64 + lane]);
#pragma unroll
    for (int o = 32; o >= 1; o >>= 1) v += __shfl_down(v, o, 64);
    if (lane == 0) out[l] = v;
}

extern "C" void kernel_launch(void* const* d_in, const int* in_sizes, int n_in,
                              void* d_out, int out_size, void* d_ws, size_t ws_size,
                              hipStream_t stream) {
    const float* x_user = (const float*)d_in[0];
    const float* x_item = (const float*)d_in[1];
    const int*   src_u  = (const int*)d_in[2];
    const int*   dst_i  = (const int*)d_in[3];
    const int*   el_src = (const int*)d_in[4];
    const int*   el_dst = (const int*)d_in[5];
    const float* Wl_ui1 = (const float*)d_in[6];
    const float* b_ui1  = (const float*)d_in[7];
    const float* Wr_ui1 = (const float*)d_in[8];
    const float* Wl_iu1 = (const float*)d_in[9];
    const float* b_iu1  = (const float*)d_in[10];
    const float* Wr_iu1 = (const float*)d_in[11];
    const float* Wl_ui2 = (const float*)d_in[12];
    const float* b_ui2  = (const float*)d_in[13];
    const float* Wr_ui2 = (const float*)d_in[14];
    const float* Wl_iu2 = (const float*)d_in[15];
    const float* b_iu2  = (const float*)d_in[16];
    const float* Wr_iu2 = (const float*)d_in[17];
    float* out = (float*)d_out;

    // ---- workspace layout (r11 offsets) ----
    int* iw     = (int*)d_ws;
    int* cnt_i  = iw;              // [0, 50000)
    int* cnt_u  = iw + 50000;      // [50000, 150000)
    int* bsum_i = iw + 150000;
    int* bsum_u = iw + 150064;
    int* head_i = iw + 150192;
    int* head_u = iw + 200192;
    int* nbr_i  = iw + 300192;
    int* nbr_u  = iw + 940192;
    char* W8 = (char*)d_ws;
    size_t off = 6320768;
    ushort_t* Bh1u = (ushort_t*)(W8 + off); off += 65536;
    ushort_t* Bl1u = (ushort_t*)(W8 + off); off += 65536;
    ushort_t* Bh1i = (ushort_t*)(W8 + off); off += 65536;
    ushort_t* Bl1i = (ushort_t*)(W8 + off); off += 65536;
    ushort_t* Bh2u = (ushort_t*)(W8 + off); off += 32768;
    ushort_t* Bl2u = (ushort_t*)(W8 + off); off += 32768;
    ushort_t* Bh2i = (ushort_t*)(W8 + off); off += 32768;
    ushort_t* Bl2i = (ushort_t*)(W8 + off); off += 32768;   // off = 6,713,984
    ushort_t* h1_u = (ushort_t*)(W8 + off); off += (size_t)NUSER * 128 * 2;
    ushort_t* h1_i = (ushort_t*)(W8 + off); off += (size_t)NITEM * 128 * 2;
    size_t YB = off;                                        // 45,113,984
    ushort_t* ymsg_u = (ushort_t*)(W8 + YB);
    ushort_t* ymsg_i = (ushort_t*)(W8 + YB + 25600000);
    ushort_t* z_u    = (ushort_t*)(W8 + YB + 38400000);
    ushort_t* z_i    = (ushort_t*)(W8 + YB + 64000000);
    ushort_t* ymsg2_u = (ushort_t*)(W8 + YB);
    ushort_t* ymsg2_i = (ushort_t*)(W8 + YB + 12800000);
    ushort_t* z2_u    = (ushort_t*)(W8 + YB + 19200000);
    ushort_t* z2_i    = (ushort_t*)(W8 + YB + 32000000);
    ushort_t* h2_u    = (ushort_t*)(W8 + YB + 38400000);
    ushort_t* h2_i    = (ushort_t*)(W8 + YB + 51200000);

    // Zero ONLY cnt (atomic-incremented); everything else written-before-read.
    hipMemsetAsync(d_ws, 0, 150000 * sizeof(int), stream);

    // ---- [degree count | weight pack] ----
    countw_kernel<<<2548, 256, 0, stream>>>(
        src_u, dst_i, cnt_u, cnt_i,
        Wl_ui1, Wr_iu1, Wl_iu1, Wr_ui1, Wl_ui2, Wr_iu2, Wl_iu2, Wr_ui2,
        Bh1u, Bl1u, Bh1i, Bl1i, Bh2u, Bl2u, Bh2i, Bl2i);

    // ---- ordered exclusive scan ----
    scan1_kernel<<<GI + GU, 256, 0, stream>>>(cnt_i, cnt_u, head_i, head_u, bsum_i, bsum_u);
    scan23_kernel<<<GI + GU, 256, 0, stream>>>(head_i, head_u, bsum_i, bsum_u);

    // ---- [binned CSR fill FIRST | layer-1 GEMM backfills] ----
    gemmfill_kernel<<<NFILL + NB1G, 512, 0, stream>>>(
        x_user, x_item, Bh1u, Bh1i,
        ymsg_u, z_u, ymsg_i, z_i,
        src_u, dst_i, head_i, head_u, nbr_i, nbr_u);

    // ---- layer 1 gather ----
    gather1_kernel<<<(NITEM + NUSER) / 4, 256, 0, stream>>>(
        ymsg_u, ymsg_i, nbr_i, head_i, cnt_i, nbr_u, head_u, cnt_u,
        z_i, z_u, b_ui1, b_iu1, h1_i, h1_u);

    // ---- layer 2 ----
    gemm2_kernel<<<NBG2, 512, 0, stream>>>(
        h1_u, h1_i, Bh2u, Bl2u, Bh2i, Bl2i,
        ymsg2_u, z2_u, ymsg2_i, z2_i);
    gather2_kernel<<<(NITEM + NUSER) / 4, 256, 0, stream>>>(
        ymsg2_u, ymsg2_i, nbr_i, head_i, cnt_i, nbr_u, head_u, cnt_u,
        z2_i, z2_u, b_ui2, b_iu2, h2_i, h2_u);

    // ---- link prediction head ----
    predict_kernel<<<NLINK / 4, 256, 0, stream>>>(el_src, el_dst, h2_u, h2_i, out);
}